// Round 1
// 134.367 us; speedup vs baseline: 1.0297x; 1.0297x over previous
//
#include <hip/hip_runtime.h>

#define DM   1024
#define HN   16
#define DKH  64
#define SEQ  2048
#define BATCH 2

typedef __attribute__((ext_vector_type(8))) __bf16 bf16x8;
typedef __attribute__((ext_vector_type(4))) float  f32x4;
typedef __attribute__((ext_vector_type(16))) float f32x16;
typedef __attribute__((ext_vector_type(2)))  int   i32x2;

#define AS1 __attribute__((address_space(1)))
#define AS3 __attribute__((address_space(3)))
#define GLL(g, l) __builtin_amdgcn_global_load_lds((const AS1 unsigned int*)(const void*)(g), \
                                                   (AS3 unsigned int*)(void*)(l), 16, 0, 0)

__device__ __forceinline__ unsigned short f2bf(float f) {
  union { float f; unsigned u; } v; v.f = f;
  unsigned u = v.u;
  u += 0x7FFFu + ((u >> 16) & 1u);   // round-to-nearest-even
  return (unsigned short)(u >> 16);
}

// ------------- prep: all fp32->bf16 conversions + mask bit-pack, 1 dispatch ----
// blocks [0,12288): activations q/k/v; [12288,16384): weights; [16384,17408): mask.
__global__ __launch_bounds__(256) void prep_kernel(
    const float* __restrict__ q, const float* __restrict__ k,
    const float* __restrict__ v,
    const float* __restrict__ Wq, const float* __restrict__ Wk,
    const float* __restrict__ Wv, const float* __restrict__ Wo,
    const int* __restrict__ mask,
    unsigned short* __restrict__ q_bf, unsigned short* __restrict__ k_bf,
    unsigned short* __restrict__ v_bf,
    unsigned short* __restrict__ Wq_bf, unsigned short* __restrict__ Wk_bf,
    unsigned short* __restrict__ Wv_bf, unsigned short* __restrict__ Wo_bf,
    unsigned* __restrict__ pkm) {
  const int bid = blockIdx.x;
  if (bid < 12288) {                       // 3 x 4096 blocks, 4 MB vec4 each
    int t = bid >> 12, r = bid & 4095;
    const float* in = (t == 0) ? q : (t == 1) ? k : v;
    unsigned short* out = (t == 0) ? q_bf : (t == 1) ? k_bf : v_bf;
    int i = r * 256 + threadIdx.x;
    float4 f = ((const float4*)in)[i];
    ushort4 o;
    o.x = f2bf(f.x); o.y = f2bf(f.y); o.z = f2bf(f.z); o.w = f2bf(f.w);
    ((ushort4*)out)[i] = o;
  } else if (bid < 16384) {                // 4 x 1024 blocks
    int b2 = bid - 12288;
    int t = b2 >> 10, r = b2 & 1023;
    const float* in = (t == 0) ? Wq : (t == 1) ? Wk : (t == 2) ? Wv : Wo;
    unsigned short* out = (t == 0) ? Wq_bf : (t == 1) ? Wk_bf : (t == 2) ? Wv_bf : Wo_bf;
    int i = r * 256 + threadIdx.x;
    float4 f = ((const float4*)in)[i];
    ushort4 o;
    o.x = f2bf(f.x); o.y = f2bf(f.y); o.z = f2bf(f.z); o.w = f2bf(f.w);
    ((ushort4*)out)[i] = o;
  } else {                                 // 1024 blocks: mask pack
    int W = (bid - 16384) * 256 + threadIdx.x;
    const int4* base = (const int4*)(mask + (size_t)(W >> 6) * SEQ + (size_t)(W & 63) * 32);
    unsigned bits = 0;
#pragma unroll
    for (int g = 0; g < 8; ++g) {
      int4 m = base[g];
      bits |= (unsigned)(m.x != 0) << (4 * g);
      bits |= (unsigned)(m.y != 0) << (4 * g + 1);
      bits |= (unsigned)(m.z != 0) << (4 * g + 2);
      bits |= (unsigned)(m.w != 0) << (4 * g + 3);
    }
    pkm[W] = bits;
  }
}

// ---- pipelined GEMM core: 128x128 tile, BK=32, 3-stage LDS, raw s_barrier ----
__device__ __forceinline__ void gemm_core_pipe(
    const unsigned short* __restrict__ A,
    const unsigned short* __restrict__ W,
    unsigned short* lds,   // 24576 shorts: stage s at s*8192, B-half at +4096
    f32x4 (&acc)[4][4]) {
  const int tid = threadIdx.x;
  const int wave = tid >> 6, lane = tid & 63;
  const int l15 = lane & 15, quad = lane >> 4;
  const int wr = wave >> 1, wc = wave & 1;

  const int rl = lane >> 2;
  const int cg = (lane & 3) ^ (((rl & 3) + ((rl >> 2) & 3)) & 3);
  const unsigned short* ga = A + (size_t)(wave * 32 + rl) * DM + cg * 8;
  const unsigned short* gb = W + (size_t)(wave * 32 + rl) * DM + cg * 8;
  unsigned short* la = lds + wave * 1024;
  unsigned short* lb = lds + 4096 + wave * 1024;

  const int cfr = (quad ^ (((l15 & 3) + ((l15 >> 2) & 3)) & 3)) * 8;

  auto stage = [&](int ki, int sb) {
    const unsigned short* a = ga + ki * 32;
    const unsigned short* b = gb + ki * 32;
    GLL(a, la + sb);                    GLL(a + (size_t)16 * DM, la + sb + 512);
    GLL(b, lb + sb);                    GLL(b + (size_t)16 * DM, lb + sb + 512);
  };
  auto compute = [&](int sb) {
    const unsigned short* Ab = lds + sb;
    const unsigned short* Bb = lds + sb + 4096;
    bf16x8 af[4], bfr[4];
#pragma unroll
    for (int mt = 0; mt < 4; ++mt)
      af[mt] = *(const bf16x8*)(Ab + (size_t)(wr * 64 + mt * 16 + l15) * 32 + cfr);
#pragma unroll
    for (int nt = 0; nt < 4; ++nt)
      bfr[nt] = *(const bf16x8*)(Bb + (size_t)(wc * 64 + nt * 16 + l15) * 32 + cfr);
#pragma unroll
    for (int mt = 0; mt < 4; ++mt)
#pragma unroll
      for (int nt = 0; nt < 4; ++nt)
        acc[mt][nt] = __builtin_amdgcn_mfma_f32_16x16x32_bf16(af[mt], bfr[nt], acc[mt][nt], 0, 0, 0);
  };

  stage(0, 0);
  stage(1, 8192);
  int sb0 = 0, sb1 = 8192, sb2 = 16384;
#pragma unroll 1
  for (int i = 0; i < DM / 32 - 2; ++i) {
    stage(i + 2, sb2);
    asm volatile("s_waitcnt vmcnt(8)\ns_barrier" ::: "memory");
    compute(sb0);
    asm volatile("s_barrier" ::: "memory");
    int t = sb0; sb0 = sb1; sb1 = sb2; sb2 = t;
  }
  asm volatile("s_waitcnt vmcnt(4)\ns_barrier" ::: "memory");
  compute(sb0);
  asm volatile("s_waitcnt vmcnt(0)\ns_barrier" ::: "memory");
  compute(sb1);
}

// Fused Q/K/V projections: grid (8, 32, 3). z=0: Q pre-scaled by 0.125*log2(e).
// z=2 (V): epilogue transposes the 128x128 tile through LDS and writes vpT
// with contiguous 16B token-runs (fixes the 4KB-stride 2B-store scatter).
__global__ __launch_bounds__(256, 3) void gemm_qkv(
    const unsigned short* __restrict__ Aq, const unsigned short* __restrict__ Ak,
    const unsigned short* __restrict__ Av,
    const unsigned short* __restrict__ Wq, const unsigned short* __restrict__ Wk,
    const unsigned short* __restrict__ Wv,
    const float* __restrict__ bq, const float* __restrict__ bk,
    const float* __restrict__ bv,
    unsigned short* __restrict__ oq, unsigned short* __restrict__ ok,
    unsigned short* __restrict__ ovT) {
  const int z = blockIdx.z;
  const unsigned short* A = (z == 0) ? Aq : (z == 1) ? Ak : Av;
  const unsigned short* W = (z == 0) ? Wq : (z == 1) ? Wk : Wv;
  const float* bias = (z == 0) ? bq : (z == 1) ? bk : bv;

  __shared__ __align__(16) unsigned short lds[24576];

  const int bn = blockIdx.x * 128, bm = blockIdx.y * 128;
  f32x4 acc[4][4] = {};
  gemm_core_pipe(A + (size_t)bm * DM, W + (size_t)bn * DM, lds, acc);

  const int tid = threadIdx.x;
  const int wave = tid >> 6, lane = tid & 63;
  const int l15 = lane & 15, quad = lane >> 4;
  const int wr = wave >> 1, wc = wave & 1;

  if (z != 2) {
    const float qs = (z == 0) ? 0.125f * 1.44269504088896f : 1.0f;
    unsigned short* out = (z == 0) ? oq : ok;
#pragma unroll
    for (int mt = 0; mt < 4; ++mt)
#pragma unroll
      for (int nt = 0; nt < 4; ++nt) {
        int col = bn + wc * 64 + nt * 16 + l15;
        float bb = bias[col];
#pragma unroll
        for (int r = 0; r < 4; ++r) {
          int row = bm + wr * 64 + mt * 16 + quad * 4 + r;
          out[(size_t)row * DM + col] = f2bf((acc[mt][nt][r] + bb) * qs);
        }
      }
  } else {
    // transpose through LDS: LT[c][tok], stride 136 shorts (16B-aligned b128 reads)
    unsigned short* LT = lds;
    __syncthreads();  // all waves done with K-loop LDS reads
#pragma unroll
    for (int mt = 0; mt < 4; ++mt)
#pragma unroll
      for (int nt = 0; nt < 4; ++nt) {
        int c = wc * 64 + nt * 16 + l15;
        float bb = bias[bn + c];
        int t0 = wr * 64 + mt * 16 + quad * 4;
        ushort4 w4;
        w4.x = f2bf(acc[mt][nt][0] + bb);
        w4.y = f2bf(acc[mt][nt][1] + bb);
        w4.z = f2bf(acc[mt][nt][2] + bb);
        w4.w = f2bf(acc[mt][nt][3] + bb);
        *(ushort4*)(LT + (size_t)c * 136 + t0) = w4;
      }
    __syncthreads();
    const int b = bm >> 11, sbase = bm & (SEQ - 1);
#pragma unroll
    for (int j = 0; j < 8; ++j) {
      int c = wave * 32 + (j >> 1) * 8 + (lane >> 3);
      int tk = (j & 1) * 64 + (lane & 7) * 8;
      bf16x8 vv = *(const bf16x8*)(LT + (size_t)c * 136 + tk);
      int C = bn + c;
      int h = C >> 6, dk = C & 63;
      *(bf16x8*)(ovT + ((size_t)((b * HN + h) * DKH + dk)) * SEQ + sbase + tk) = vv;
    }
  }
}

// Output projection: fp32 out. grid (8, 32).
__global__ __launch_bounds__(256, 3) void gemm_wo(
    const unsigned short* __restrict__ A, const unsigned short* __restrict__ W,
    const float* __restrict__ bias, float* __restrict__ out) {
  __shared__ __align__(16) unsigned short lds[24576];

  const int bn = blockIdx.x * 128, bm = blockIdx.y * 128;
  f32x4 acc[4][4] = {};
  gemm_core_pipe(A + (size_t)bm * DM, W + (size_t)bn * DM, lds, acc);

  const int tid = threadIdx.x;
  const int wave = tid >> 6, lane = tid & 63;
  const int l15 = lane & 15, quad = lane >> 4;
  const int wr = wave >> 1, wc = wave & 1;

#pragma unroll
  for (int mt = 0; mt < 4; ++mt)
#pragma unroll
    for (int nt = 0; nt < 4; ++nt) {
      int col = bn + wc * 64 + nt * 16 + l15;
      float bb = bias[col];
#pragma unroll
      for (int r = 0; r < 4; ++r) {
        int row = bm + wr * 64 + mt * 16 + quad * 4 + r;
        out[(size_t)row * DM + col] = acc[mt][nt][r] + bb;
      }
    }
}

// ---------------- flash attention, 32x32x16 MFMA ----------------
// Each wave owns 32 queries (query = lane&31 via swapped QK^T), 4 waves = 128 q/block.
// Grid (B*H, SEQ/128) = (32,16) -> 2 blocks/CU. LDS: K[64key][64d] + V^T[64d][64key],
// both double-buffered, XOR-swizzled (slot ^= row&7) on both GLL source and ds_read.
// LDS bytes per query per tile HALVED vs the 16x16x32 version (the prior bottleneck:
// ~41us of 59us was LDS->reg operand traffic).
__global__ __launch_bounds__(256, 2) void attn_kernel(
    const unsigned short* __restrict__ qp,
    const unsigned short* __restrict__ kp,
    const unsigned short* __restrict__ vpT,
    const unsigned* __restrict__ pk,
    unsigned short* __restrict__ ctx) {
  const int lane = threadIdx.x & 63;
  const int wave = threadIdx.x >> 6;
  const int l31 = lane & 31, hi = lane >> 5, l7 = lane & 7;
  const int bh = blockIdx.x;
  const int b = bh >> 4, h = bh & 15;
  const int qrow = blockIdx.y * 128 + wave * 32 + l31;

  __shared__ __align__(16) unsigned short lds[16384];

  // Q fragments (B-operand): element j = Q[qrow][kt*16 + hi*8 + j], pre-scaled.
  const unsigned short* qb = qp + ((size_t)(b * SEQ + qrow)) * DM + h * DKH + hi * 8;
  bf16x8 qf[4];
#pragma unroll
  for (int kt = 0; kt < 4; ++kt) qf[kt] = *(const bf16x8*)(qb + kt * 16);

  f32x16 o0 = {}, o1 = {}, lacc = {};
  bf16x8 ones;
#pragma unroll
  for (int i = 0; i < 8; ++i) ones[i] = (__bf16)1.0f;

  // staging: each GLL covers 8 rows x 128B; phys slot (l&7) holds logical
  // slot (l&7)^(row&7)  (row&7 == (l>>3)&7) -> pre-swizzled global source.
  const int r8 = lane >> 3;
  const int cg = (l7 ^ r8) * 8;
  const unsigned short* kg0 = kp + ((size_t)(b * SEQ + wave * 16 + r8)) * DM + h * DKH + cg;
  const unsigned short* kg1 = kg0 + (size_t)8 * DM;
  const unsigned short* vg0 = vpT + ((size_t)(bh * DKH + wave * 16 + r8)) * SEQ + cg;
  const unsigned short* vg1 = vg0 + (size_t)8 * SEQ;
  unsigned short* lK = lds + wave * 1024;
  unsigned short* lV = lds + 8192 + wave * 1024;

  // ds_read offsets (shorts): row = sub*32 + l31, 16B slot = (x*2+hi)^(row&7).
  // Consecutive 8 lanes hit 8 distinct slots -> all 32 banks, conflict-free.
  int roff[4];
#pragma unroll
  for (int x = 0; x < 4; ++x)
    roff[x] = l31 * 64 + (((x * 2 + hi) ^ l7) * 8);

  const unsigned* mb = pk + (size_t)(b * SEQ + qrow) * (SEQ / 32);

  // T12: scores (row r -> key (r&3)+8*(r>>2)+4*hi) -> exp2 -> masked ->
  // cvt_pk pairs + permlane32_swap -> two PV A-fragments (16 keys each).
  auto make_pa = [&](const f32x16& sc, unsigned bits, bf16x8& paA, bf16x8& paB) {
    float p[16];
#pragma unroll
    for (int r = 0; r < 16; ++r) {
      float e = __builtin_amdgcn_exp2f(sc[r]);
      p[r] = ((bits >> ((r & 3) + 8 * (r >> 2))) & 1u) ? e : 0.0f;
    }
    unsigned X0, X1, Y0, Y1;
    asm("v_cvt_pk_bf16_f32 %0, %1, %2" : "=v"(X0) : "v"(p[0]), "v"(p[1]));
    asm("v_cvt_pk_bf16_f32 %0, %1, %2" : "=v"(X1) : "v"(p[2]), "v"(p[3]));
    asm("v_cvt_pk_bf16_f32 %0, %1, %2" : "=v"(Y0) : "v"(p[4]), "v"(p[5]));
    asm("v_cvt_pk_bf16_f32 %0, %1, %2" : "=v"(Y1) : "v"(p[6]), "v"(p[7]));
    i32x2 s0 = __builtin_amdgcn_permlane32_swap((int)X0, (int)Y0, false, false);
    i32x2 s1 = __builtin_amdgcn_permlane32_swap((int)X1, (int)Y1, false, false);
    union { unsigned u[4]; bf16x8 v; } ua;
    ua.u[0] = (unsigned)s0.x; ua.u[1] = (unsigned)s1.x;
    ua.u[2] = (unsigned)s0.y; ua.u[3] = (unsigned)s1.y;
    paA = ua.v;
    asm("v_cvt_pk_bf16_f32 %0, %1, %2" : "=v"(X0) : "v"(p[8]),  "v"(p[9]));
    asm("v_cvt_pk_bf16_f32 %0, %1, %2" : "=v"(X1) : "v"(p[10]), "v"(p[11]));
    asm("v_cvt_pk_bf16_f32 %0, %1, %2" : "=v"(Y0) : "v"(p[12]), "v"(p[13]));
    asm("v_cvt_pk_bf16_f32 %0, %1, %2" : "=v"(Y1) : "v"(p[14]), "v"(p[15]));
    s0 = __builtin_amdgcn_permlane32_swap((int)X0, (int)Y0, false, false);
    s1 = __builtin_amdgcn_permlane32_swap((int)X1, (int)Y1, false, false);
    union { unsigned u[4]; bf16x8 v; } ub;
    ub.u[0] = (unsigned)s0.x; ub.u[1] = (unsigned)s1.x;
    ub.u[2] = (unsigned)s0.y; ub.u[3] = (unsigned)s1.y;
    paB = ub.v;
  };

  auto compute_tile = [&](int j0, const unsigned short* Kb, const unsigned short* Vb) {
    uint2 mw = *(const uint2*)(mb + (j0 >> 5));
    unsigned bx = mw.x >> (4 * hi);
    unsigned by = mw.y >> (4 * hi);

    // QK^T: A = K (key = sub*32 + l31), B = Q (query = l31). 8 MFMAs.
    f32x16 sc0 = {}, sc1 = {};
#pragma unroll
    for (int kt = 0; kt < 4; ++kt) {
      bf16x8 k0 = *(const bf16x8*)(Kb + roff[kt]);
      bf16x8 k1 = *(const bf16x8*)(Kb + 2048 + roff[kt]);
      sc0 = __builtin_amdgcn_mfma_f32_32x32x16_bf16(k0, qf[kt], sc0, 0, 0, 0);
      sc1 = __builtin_amdgcn_mfma_f32_32x32x16_bf16(k1, qf[kt], sc1, 0, 0, 0);
    }

    bf16x8 pa[4];
    make_pa(sc0, bx, pa[0], pa[1]);
    make_pa(sc1, by, pa[2], pa[3]);

    // l = sum_k P[q][k] via ones-MFMA: rows align with O's rows for free norm.
#pragma unroll
    for (int kc = 0; kc < 4; ++kc)
      lacc = __builtin_amdgcn_mfma_f32_32x32x16_bf16(pa[kc], ones, lacc, 0, 0, 0);

    // PV: A = P, B = V^T rows (d = dsub*32 + l31). 8 MFMAs.
#pragma unroll
    for (int kc = 0; kc < 4; ++kc) {
      bf16x8 v0 = *(const bf16x8*)(Vb + roff[kc]);
      bf16x8 v1 = *(const bf16x8*)(Vb + 2048 + roff[kc]);
      o0 = __builtin_amdgcn_mfma_f32_32x32x16_bf16(pa[kc], v0, o0, 0, 0, 0);
      o1 = __builtin_amdgcn_mfma_f32_32x32x16_bf16(pa[kc], v1, o1, 0, 0, 0);
    }
  };

  GLL(kg0, lK);           GLL(kg1, lK + 512);
  GLL(vg0, lV);           GLL(vg1, lV + 512);

#pragma unroll 1
  for (int j0 = 0; j0 < SEQ; j0 += 128) {
    __syncthreads();
    if (j0 + 64 < SEQ) {
      GLL(kg0 + (size_t)(j0 + 64) * DM, lK + 4096);
      GLL(kg1 + (size_t)(j0 + 64) * DM, lK + 4096 + 512);
      GLL(vg0 + (j0 + 64), lV + 4096);
      GLL(vg1 + (j0 + 64), lV + 4096 + 512);
    }
    compute_tile(j0, lds, lds + 8192);

    __syncthreads();
    if (j0 + 128 < SEQ) {
      GLL(kg0 + (size_t)(j0 + 128) * DM, lK);
      GLL(kg1 + (size_t)(j0 + 128) * DM, lK + 512);
      GLL(vg0 + (j0 + 128), lV);
      GLL(vg1 + (j0 + 128), lV + 512);
    }
    compute_tile(j0 + 64, lds + 4096, lds + 12288);
  }

  // epilogue: reg r -> query qbase + (r&3) + 8*(r>>2) + 4*hi; d = dsub*32 + l31.
  const int qbase = blockIdx.y * 128 + wave * 32;
#pragma unroll
  for (int r = 0; r < 16; ++r) {
    int qg = qbase + (r & 3) + 8 * (r >> 2) + 4 * hi;
    float inv = 1.0f / lacc[r];
    unsigned short* op = ctx + ((size_t)(b * SEQ + qg)) * DM + h * DKH + l31;
    op[0]  = f2bf(o0[r] * inv);
    op[32] = f2bf(o1[r] * inv);
  }
}

// ---------------- launch ----------------
extern "C" void kernel_launch(void* const* d_in, const int* in_sizes, int n_in,
                              void* d_out, int out_size, void* d_ws, size_t ws_size,
                              hipStream_t stream) {
  const float* q    = (const float*)d_in[0];
  const float* k    = (const float*)d_in[1];
  const float* v    = (const float*)d_in[2];
  const int*   mask = (const int*)d_in[3];
  const float* Wq_w = (const float*)d_in[4];
  const float* Wq_b = (const float*)d_in[5];
  const float* Wk_w = (const float*)d_in[6];
  const float* Wk_b = (const float*)d_in[7];
  const float* Wv_w = (const float*)d_in[8];
  const float* Wv_b = (const float*)d_in[9];
  const float* Wo_w = (const float*)d_in[10];
  const float* Wo_b = (const float*)d_in[11];

  char* ws = (char*)d_ws;
  const size_t MB = 1024 * 1024;
  unsigned short* q_bf  = (unsigned short*)(ws + 0 * MB);
  unsigned short* k_bf  = (unsigned short*)(ws + 8 * MB);
  unsigned short* v_bf  = (unsigned short*)(ws + 16 * MB);
  unsigned short* Wq_bf = (unsigned short*)(ws + 24 * MB);
  unsigned short* Wk_bf = (unsigned short*)(ws + 26 * MB);
  unsigned short* Wv_bf = (unsigned short*)(ws + 28 * MB);
  unsigned short* Wo_bf = (unsigned short*)(ws + 30 * MB);
  unsigned short* qp    = (unsigned short*)(ws + 32 * MB);
  unsigned short* kp    = (unsigned short*)(ws + 40 * MB);
  unsigned short* vpT   = (unsigned short*)(ws + 48 * MB);
  unsigned short* ctx   = (unsigned short*)(ws + 56 * MB);
  // packed mask lives in d_out scratch (16 MB fp32): consumed by attn_kernel,
  // which completes before gemm_wo writes d_out (stream-ordered). 1 MB needed.
  unsigned* pkm = (unsigned*)d_out;

  const int M = BATCH * SEQ;  // 4096

  prep_kernel<<<17408, 256, 0, stream>>>(q, k, v, Wq_w, Wk_w, Wv_w, Wo_w, mask,
                                         q_bf, k_bf, v_bf, Wq_bf, Wk_bf, Wv_bf,
                                         Wo_bf, pkm);

  gemm_qkv<<<dim3(DM / 128, M / 128, 3), 256, 0, stream>>>(
      q_bf, k_bf, v_bf, Wq_bf, Wk_bf, Wv_bf, Wq_b, Wk_b, Wv_b, qp, kp, vpT);

  attn_kernel<<<dim3(BATCH * HN, SEQ / 128), 256, 0, stream>>>(qp, kp, vpT, pkm, ctx);

  gemm_wo<<<dim3(DM / 128, M / 128), 256, 0, stream>>>(ctx, Wo_bf, Wo_b, (float*)d_out);
}